// Round 2
// baseline (156.158 us; speedup 1.0000x reference)
//
#include <hip/hip_runtime.h>

// LFR frame stacking: x (B=64, T=4096, D=80) f32, lens (B,) i32
// out (B, NF=683, M*D=560) f32 ++ new_len (B,) f32
//
// Derived semantics (verified, absmax 0.0): T_all_max = 4099 fixed (lens[0]=T),
// NF = (4099-7)/6+1 = 683. Gather index for output position t=6f+m:
//   src = 0 if t<3; t-3 if t<3+lens[b]; else T-1.
//
// Round 2: kernel inferred ~33us vs ~23us mixed-stream floor (147 MB).
// Lever: MLP. 4-way unroll at +256 stride; all 4 loads issued before any
// store (4x16B outstanding per thread). NT stores kept (write-once stream,
// keep x resident in L2 for frame-overlap + clamp-broadcast re-reads).
// If neutral: kernel is at the mixed read/write ceiling; residual total
// time is harness fill (2x ~57-60us) + tiny reset dispatches.

typedef float __attribute__((ext_vector_type(4))) f32x4;

constexpr int B    = 64;
constexpr int T    = 4096;
constexpr int D    = 80;
constexpr int NF   = 683;
constexpr int M    = 7;
constexpr int N    = 6;
constexpr int LEFT = 3;

constexpr int D4     = D / 4;         // 20 float4 per frame
constexpr int ROW4   = M * D4;        // 140 float4 per output row
constexpr int TOTAL4 = B * NF * ROW4; // 6,119,680 float4 total

__device__ __forceinline__ int src_index(int idx, const int* __restrict__ lens) {
    int row = idx / ROW4;          // (b, f) flat
    int r   = idx - row * ROW4;    // position within row, [0,140)
    int b   = row / NF;
    int f   = row - b * NF;
    int m   = r / D4;              // which of M frames
    int d4  = r - m * D4;          // float4 within frame
    int t   = f * N + m;           // gather position in padded time axis
    int L   = lens[b];
    int src = (t < LEFT) ? 0 : (t < LEFT + L) ? (t - LEFT) : (T - 1);
    return (b * T + src) * D4 + d4;
}

__global__ __launch_bounds__(256) void lfr_kernel(
    const f32x4* __restrict__ x,      // (B*T*D4) float4
    const int*   __restrict__ lens,   // (B,)
    f32x4*       __restrict__ out,    // (B*NF*ROW4) float4
    float*       __restrict__ new_len) // (B,)
{
    // fused tiny output: new_len
    if (blockIdx.x == 0 && threadIdx.x < B) {
        int L   = lens[threadIdx.x];
        int rem = L % N;
        int rp  = (rem == 1) ? 3 : (rem == 2) ? 2 : (rem == 3) ? 1 : 0;
        new_len[threadIdx.x] = (float)((LEFT + L + rp) / N);
    }

    int base = blockIdx.x * 1024 + (int)threadIdx.x;

    int  idx[4];
    bool ok[4];
    f32x4 v[4];

    #pragma unroll
    for (int u = 0; u < 4; ++u) {
        idx[u] = base + u * 256;
        ok[u]  = idx[u] < TOTAL4;
    }

    // Issue all loads before any store — 4x16B outstanding per thread.
    #pragma unroll
    for (int u = 0; u < 4; ++u)
        if (ok[u]) v[u] = x[src_index(idx[u], lens)];

    #pragma unroll
    for (int u = 0; u < 4; ++u)
        if (ok[u]) __builtin_nontemporal_store(v[u], &out[idx[u]]);
}

extern "C" void kernel_launch(void* const* d_in, const int* in_sizes, int n_in,
                              void* d_out, int out_size, void* d_ws, size_t ws_size,
                              hipStream_t stream) {
    const f32x4* x    = (const f32x4*)d_in[0];
    const int*   lens = (const int*)d_in[1];
    float*        out = (float*)d_out;
    float*        nl  = out + (size_t)B * NF * M * D; // new_len after main output

    int blocks = (TOTAL4 + 1023) / 1024; // 5977
    lfr_kernel<<<blocks, 256, 0, stream>>>(x, lens, (f32x4*)out, nl);
}